// Round 10
// baseline (195.853 us; speedup 1.0000x reference)
//
#include <hip/hip_runtime.h>
#include <hip/hip_bf16.h>
#include <stdint.h>

// B=4, S=8192, E=1024, heads=16 -> math collapses to:
//   Q = x @ W1[0:1024].T ; A = per-64-col-block softmax(Q/4) ; out = A @ W2.T
static constexpr int MTOT = 32768;
static constexpr int KD   = 1024;
static constexpr int ND   = 1024;

static constexpr int BM = 128, BN = 128, BK = 64;
static constexpr int NT = KD / BK;              // 16 K-tiles (even)
static constexpr int BUF_BYTES = 32768;         // per-buffer: A 16K + B 16K
static constexpr int BOFF = 16384;              // B offset within buffer

typedef __bf16 bf16x8 __attribute__((ext_vector_type(8)));
typedef float  f32x4  __attribute__((ext_vector_type(4)));

__device__ __forceinline__ unsigned short f2bf_rne(float f) {
  union { float f; uint32_t u; } c; c.f = f;
  uint32_t u = c.u;
  return (unsigned short)((u + 0x7fffu + ((u >> 16) & 1u)) >> 16);
}

__global__ void cast_f32_to_bf16(const float* __restrict__ src,
                                 unsigned short* __restrict__ dst, int n4) {
  int idx = blockIdx.x * blockDim.x + threadIdx.x;
  int stride = gridDim.x * blockDim.x;
  for (int i = idx; i < n4; i += stride) {
    float4 v = reinterpret_cast<const float4*>(src)[i];
    ushort4 o;
    o.x = f2bf_rne(v.x); o.y = f2bf_rne(v.y);
    o.z = f2bf_rne(v.z); o.w = f2bf_rne(v.w);
    reinterpret_cast<ushort4*>(dst)[i] = o;
  }
}

__device__ __forceinline__ void gload_lds16(const void* g, void* lds) {
  __builtin_amdgcn_global_load_lds(
      (const __attribute__((address_space(1))) unsigned int*)g,
      (__attribute__((address_space(3))) unsigned int*)lds, 16, 0, 0);
}

// r10: 128x128 tile, BK=64, 4 waves (2Mx2N, wave 64x64), 64 KiB LDS ->
// 2 blocks/CU resident (one block's epilogue/prologue overlaps the other's
// K-loop). Carries r7-proven: T1 XCD swizzle, T2 LDS swizzle (0 conflicts),
// counted vmcnt (never 0 in loop), 3 barriers/K-tile, setprio, 16x16x32 MFMA.
template <int SOFTMAX>
__global__ __launch_bounds__(256, 2)
void gemm4(const unsigned short* __restrict__ A,
           const unsigned short* __restrict__ Bm,
           void* __restrict__ Cout) {
  extern __shared__ __align__(16) char ldsc[];

  const int tid  = threadIdx.x;
  const int lane = tid & 63;
  const int wid  = tid >> 6;                   // 0..3
  const int wm = wid >> 1, wn = wid & 1;       // wave tile: 64 rows x 64 cols
  const int fr = lane & 15, fq = lane >> 4;

  // T1: bijective XCD swizzle (2048 blocks, 8 XCDs, 256 blocks/chunk).
  // Consecutive logical ids share a brow (8 bcols) -> A-panel L2 locality;
  // each XCD's B working set = full W panel (2 MB bf16) fits its 4 MB L2.
  const int bid0 = blockIdx.x;
  const int bid  = ((bid0 & 7) << 8) | (bid0 >> 3);
  const int brow = (bid >> 3) * BM;            // 256 row tiles
  const int bcol = (bid & 7) * BN;             // 8 col tiles

  // staging: linear LDS dest + inverse-swizzled global src (rule #21).
  // 256 threads: srow = tid>>3 (0..31), 8 slots x 16B = 128B row (=BK bf16).
  const int srow  = tid >> 3;
  const int sslot = (tid & 7) ^ (srow & 7);
  const unsigned short* gA = A  + (size_t)(brow + srow) * KD + sslot * 8;
  const unsigned short* gB = Bm + (size_t)(bcol + srow) * KD + sslot * 8;

  f32x4  acc[4][4] = {};
  bf16x8 a[4][2], bA[2][2], bB[2][2];

  // Stage one operand tile (128 rows x 64 cols = 16 KB) as 4 x 4KB issues.
  auto STAGE = [&](const unsigned short* g, int kt, int b, int opOff) {
    #pragma unroll
    for (int i = 0; i < 4; ++i)
      gload_lds16(g + (size_t)(i * 32) * KD + kt * BK,
                  ldsc + b * BUF_BYTES + opOff + i * 4096 + tid * 16);
  };

  auto rdA = [&](int b) {
    const char* base = ldsc + b * BUF_BYTES;
    #pragma unroll
    for (int m = 0; m < 4; ++m) {
      const int r = wm * 64 + m * 16 + fr;
      #pragma unroll
      for (int ks = 0; ks < 2; ++ks)
        a[m][ks] = *(const bf16x8*)(base + (r << 7) +
                     ((ks * 64 + fq * 16) ^ ((r & 7) << 4)));
    }
  };
  auto rdB = [&](int b, int nBase, bf16x8 (*dst)[2]) {
    const char* base = ldsc + b * BUF_BYTES + BOFF;
    #pragma unroll
    for (int nn = 0; nn < 2; ++nn) {
      const int r = wn * 64 + (nBase + nn) * 16 + fr;
      #pragma unroll
      for (int ks = 0; ks < 2; ++ks)
        dst[nn][ks] = *(const bf16x8*)(base + (r << 7) +
                       ((ks * 64 + fq * 16) ^ ((r & 7) << 4)));
    }
  };
  auto MFMA16 = [&](int nBase, bf16x8 (*bf)[2]) {
    __builtin_amdgcn_s_setprio(1);
    #pragma unroll
    for (int ks = 0; ks < 2; ++ks)
      #pragma unroll
      for (int mm = 0; mm < 4; ++mm)
        #pragma unroll
        for (int nn = 0; nn < 2; ++nn)
          acc[mm][nBase + nn] = __builtin_amdgcn_mfma_f32_16x16x32_bf16(
              a[mm][ks], bf[nn][ks], acc[mm][nBase + nn], 0, 0, 0);
    __builtin_amdgcn_s_setprio(0);
  };

  // K-tile step, compile-time buffer parity. Barriers: P1-end, P2-mid, P2-end.
  //  Hazards: cur.A reads (P1) retire pre-P1-end; STAGE A(T+2)->cur after it.
  //  cur.B(n23) reads (P2) retire pre-P2-end; STAGE B->that region next tile P1.
  //  nxt.B01 reads (P2, post-vmcnt-barrier) retire pre-P2-end.
  //  vmcnt queue at P2: [A(T+1)x4, B(T+1)x4, A(T+2)x4] -> vmcnt(4) retires
  //  tile T+1 fully, keeps A(T+2) in flight. Never 0 in the loop.
  auto tileStep = [&](int T, int cur, int nxt) {
    const int tp1 = (T + 1 < NT) ? T + 1 : NT - 1;
    const int tp2 = (T + 2 < NT) ? T + 2 : NT - 1;

    rdA(cur);
    STAGE(gB, tp1, nxt, BOFF);
    MFMA16(0, bA);
    __builtin_amdgcn_s_barrier();            // P1-end

    rdB(cur, 2, bB);
    STAGE(gA, tp2, cur, 0);
    asm volatile("s_waitcnt vmcnt(4)" ::: "memory");
    __builtin_amdgcn_s_barrier();            // P2-mid: tile T+1 visible to all
    rdB(nxt, 0, bA);                         // tile T+1 b01; overlaps MFMA below
    MFMA16(2, bB);
    __builtin_amdgcn_s_barrier();            // P2-end
  };

  // --- prologue: tile0 (A+B) + tile1 A ---
  STAGE(gA, 0, 0, 0);
  STAGE(gB, 0, 0, BOFF);
  STAGE(gA, 1, 1, 0);
  asm volatile("s_waitcnt vmcnt(4)" ::: "memory");   // tile0 landed; A(1) in flight
  __builtin_amdgcn_s_barrier();
  rdB(0, 0, bA);                                     // b01 of tile 0

  for (int T = 0; T < NT; T += 2) {
    tileStep(T,     0, 1);
    tileStep(T + 1, 1, 0);
  }

  if constexpr (SOFTMAX) {
    // logits = acc/4; softmax over the wave's 64-col block (= one head block)
    unsigned short* attn = reinterpret_cast<unsigned short*>(Cout);
    constexpr float CEXP = 0.25f * 1.44269504088896340736f; // log2(e)/4
    #pragma unroll
    for (int m = 0; m < 4; ++m) {
      const int row = brow + wm * 64 + m * 16 + fq * 4;
      #pragma unroll
      for (int j = 0; j < 4; ++j) {
        float v0 = acc[m][0][j], v1 = acc[m][1][j];
        float v2 = acc[m][2][j], v3 = acc[m][3][j];
        float mx = fmaxf(fmaxf(v0, v1), fmaxf(v2, v3));
        #pragma unroll
        for (int s = 1; s < 16; s <<= 1) mx = fmaxf(mx, __shfl_xor(mx, s, 64));
        float p0 = exp2f((v0 - mx) * CEXP);
        float p1 = exp2f((v1 - mx) * CEXP);
        float p2 = exp2f((v2 - mx) * CEXP);
        float p3 = exp2f((v3 - mx) * CEXP);
        float sm = p0 + p1 + p2 + p3;
        #pragma unroll
        for (int s = 1; s < 16; s <<= 1) sm += __shfl_xor(sm, s, 64);
        const float inv = 1.0f / sm;
        unsigned short* dst =
            attn + (size_t)(row + j) * ND + (bcol + wn * 64 + fr);
        dst[0]  = f2bf_rne(p0 * inv);
        dst[16] = f2bf_rne(p1 * inv);
        dst[32] = f2bf_rne(p2 * inv);
        dst[48] = f2bf_rne(p3 * inv);
      }
    }
  } else {
    float* Cf = reinterpret_cast<float*>(Cout);
    #pragma unroll
    for (int m = 0; m < 4; ++m) {
      const int row = brow + wm * 64 + m * 16 + fq * 4;
      #pragma unroll
      for (int n = 0; n < 4; ++n) {
        const int col = bcol + wn * 64 + n * 16 + fr;
        #pragma unroll
        for (int j = 0; j < 4; ++j)
          Cf[(size_t)(row + j) * ND + col] = acc[m][n][j];
      }
    }
  }
}

extern "C" void kernel_launch(void* const* d_in, const int* in_sizes, int n_in,
                              void* d_out, int out_size, void* d_ws, size_t ws_size,
                              hipStream_t stream) {
  const float* x  = (const float*)d_in[0];   // [4,8192,1024] f32
  const float* W1 = (const float*)d_in[1];   // [3072,1024]  f32 (rows 0..1023 = Wq)
  const float* W2 = (const float*)d_in[2];   // [1024,1024]  f32
  float* out = (float*)d_out;

  char* ws = (char*)d_ws;
  unsigned short* xb   = (unsigned short*)(ws);
  unsigned short* w1b  = (unsigned short*)(ws + (size_t)67108864);
  unsigned short* w2b  = (unsigned short*)(ws + (size_t)69206016);
  unsigned short* attn = (unsigned short*)(ws + (size_t)71303168);

  hipFuncSetAttribute(reinterpret_cast<const void*>(gemm4<1>),
                      hipFuncAttributeMaxDynamicSharedMemorySize, 65536);
  hipFuncSetAttribute(reinterpret_cast<const void*>(gemm4<0>),
                      hipFuncAttributeMaxDynamicSharedMemorySize, 65536);

  cast_f32_to_bf16<<<2048, 256, 0, stream>>>(x,  xb,  MTOT * KD / 4);
  cast_f32_to_bf16<<<512,  256, 0, stream>>>(W1, w1b, KD * KD / 4);
  cast_f32_to_bf16<<<512,  256, 0, stream>>>(W2, w2b, KD * KD / 4);

  const int nblk = (MTOT / BM) * (ND / BN);   // 256 * 8 = 2048
  gemm4<1><<<nblk, 256, 65536, stream>>>(xb, w1b, (void*)attn);
  gemm4<0><<<nblk, 256, 65536, stream>>>(attn, w2b, (void*)out);
}